// Round 1
// baseline (219.741 us; speedup 1.0000x reference)
//
#include <hip/hip_runtime.h>
#include <math.h>

#define SS 2048
#define DD 256
#define NB 4
#define NR (NB * SS)  // 8192 rows total

// ---------- K0: A = Wq^T @ Wk (256x256), u = Wk^T @ bq ----------
__global__ __launch_bounds__(256) void prep_kernel(
    const float* __restrict__ Wq, const float* __restrict__ Wk,
    const float* __restrict__ bq, float* __restrict__ A, float* __restrict__ u) {
    int t = threadIdx.x;
    int d = blockIdx.x;
    if (d < DD) {
        float acc = 0.0f;
        for (int i = 0; i < DD; i++) acc += Wq[i * DD + d] * Wk[i * DD + t];
        A[d * DD + t] = acc;
    } else {
        float acc = 0.0f;
        for (int i = 0; i < DD; i++) acc += Wk[i * DD + t] * bq[i];
        u[t] = acc;
    }
}

// ---------- K1: fused LayerNorm + Y = Xn@A + u + neighbor-score softmax ----
// Block handles rows row0..row0+31. LN computed in-block for 34 rows
// (2 halo) into LDS. Then 32x256 GEMM tile in registers, then
// d = y . (xn_next - xn_prev) from LDS halo rows.
// pvals[r] = {p_next, p_prev, p_diag, 0}
#define BK 32
#define XP 260  // padded row stride: (2*260)%32=8 spreads row-broadcast banks
#define FMA4(accv, a, bv) \
    accv.x += (a) * bv.x; accv.y += (a) * bv.y; \
    accv.z += (a) * bv.z; accv.w += (a) * bv.w;

__global__ __launch_bounds__(256) void gemm_score_kernel(
    const float4* __restrict__ ctx4, const float4* __restrict__ ln_a4,
    const float4* __restrict__ ln_b4, const float* __restrict__ A,
    const float* __restrict__ u, const int* __restrict__ eos,
    float4* __restrict__ pvals) {
    __shared__ float Xn[34][XP];   // LN'd rows row0-1 .. row0+32 (~35 KB)
    __shared__ float As[BK][256];  // 32 KB
    int tid = threadIdx.x;
    int lane = tid & 63;
    int wave = tid >> 6;
    int row0 = blockIdx.x * 32;
    const float4* A4 = (const float4*)A;

    // ---- Phase 1: LayerNorm 34 rows (one wave per row, strided) ----
    float4 ga = ln_a4[lane], gb = ln_b4[lane];
    for (int rr = wave; rr < 34; rr += 4) {
        int g = row0 - 1 + rr;
        g = (g < 0) ? 0 : (g > NR - 1 ? NR - 1 : g);  // clamp (halo masked later)
        float4 v = ctx4[(size_t)g * 64 + lane];
        float s = v.x + v.y + v.z + v.w;
#pragma unroll
        for (int off = 32; off > 0; off >>= 1) s += __shfl_xor(s, off, 64);
        float mean = s * (1.0f / 256.0f);
        float4 dd = make_float4(v.x - mean, v.y - mean, v.z - mean, v.w - mean);
        float s2 = dd.x * dd.x + dd.y * dd.y + dd.z * dd.z + dd.w * dd.w;
#pragma unroll
        for (int off = 32; off > 0; off >>= 1) s2 += __shfl_xor(s2, off, 64);
        float inv = 1.0f / (sqrtf(s2 * (1.0f / 255.0f)) + 1e-6f);  // ddof=1
        float* xr = &Xn[rr][lane * 4];
        xr[0] = ga.x * dd.x * inv + gb.x;
        xr[1] = ga.y * dd.y * inv + gb.y;
        xr[2] = ga.z * dd.z * inv + gb.z;
        xr[3] = ga.w * dd.w * inv + gb.w;
    }

    // ---- Phase 2: GEMM, acc[i][q] = Y[row0+ty*2+i][64q + tx*4 .. +3] ----
    int tx = tid & 15, ty = tid >> 4;
    float4 acc[2][4] = {};
    for (int k0 = 0; k0 < DD; k0 += BK) {
#pragma unroll
        for (int q = 0; q < 8; q++) {  // stage A tile 32x256
            int f4 = q * 256 + tid;
            int k = f4 >> 6, c4 = f4 & 63;
            *(float4*)&As[k][c4 * 4] = A4[(size_t)(k0 + k) * 64 + c4];
        }
        __syncthreads();
#pragma unroll
        for (int k = 0; k < BK; k++) {
            float a0 = Xn[1 + ty * 2][k0 + k];      // row-broadcast reads
            float a1 = Xn[2 + ty * 2][k0 + k];
            float4 b0 = *(const float4*)&As[k][tx * 4];
            float4 b1 = *(const float4*)&As[k][tx * 4 + 64];
            float4 b2 = *(const float4*)&As[k][tx * 4 + 128];
            float4 b3 = *(const float4*)&As[k][tx * 4 + 192];
            FMA4(acc[0][0], a0, b0) FMA4(acc[0][1], a0, b1)
            FMA4(acc[0][2], a0, b2) FMA4(acc[0][3], a0, b3)
            FMA4(acc[1][0], a1, b0) FMA4(acc[1][1], a1, b1)
            FMA4(acc[1][2], a1, b2) FMA4(acc[1][3], a1, b3)
        }
        __syncthreads();
    }
    // ---- Phase 3: bias, neighbor diff from LDS, reduce, softmax ----
    const float4* u4 = (const float4*)u;
#pragma unroll
    for (int q = 0; q < 4; q++) {
        float4 uv = u4[q * 16 + tx];
        acc[0][q].x += uv.x; acc[0][q].y += uv.y; acc[0][q].z += uv.z; acc[0][q].w += uv.w;
        acc[1][q].x += uv.x; acc[1][q].y += uv.y; acc[1][q].z += uv.z; acc[1][q].w += uv.w;
    }
#pragma unroll
    for (int i = 0; i < 2; i++) {
        int li = 1 + ty * 2 + i;           // local row index in Xn
        int r = row0 + ty * 2 + i;
        int s = r & (SS - 1), b = r >> 11;
        bool has_n = (s < SS - 1), has_p = (s > 0);
        float fn = has_n ? 1.0f : 0.0f, fp = has_p ? 1.0f : 0.0f;
        float partial = 0.0f;
#pragma unroll
        for (int q = 0; q < 4; q++) {
            int c = q * 64 + tx * 4;
            float wx = fn * Xn[li + 1][c + 0] - fp * Xn[li - 1][c + 0];
            float wy = fn * Xn[li + 1][c + 1] - fp * Xn[li - 1][c + 1];
            float wz = fn * Xn[li + 1][c + 2] - fp * Xn[li - 1][c + 2];
            float ww = fn * Xn[li + 1][c + 3] - fp * Xn[li - 1][c + 3];
            partial += acc[i][q].x * wx + acc[i][q].y * wy
                     + acc[i][q].z * wz + acc[i][q].w * ww;
        }
#pragma unroll
        for (int off = 8; off > 0; off >>= 1) partial += __shfl_xor(partial, off, 64);
        if (tx == 0) {
            size_t base = (size_t)b * SS * SS + (size_t)s * SS;
            bool mn = has_n && (eos[base + s + 1] != 0);
            bool mp = has_p && (eos[base + s - 1] != 0);
            float pn, pp, pd;
            if (mn && mp) {
                float d = partial * (1.0f / 256.0f);  // (s_next - s_prev)
                pn = 1.0f / (1.0f + __expf(-d));
                pp = 1.0f - pn;
                pd = 0.0f;
            } else if (mn) { pn = 1.0f; pp = 0.0f; pd = 0.0f; }
            else if (mp)   { pn = 0.0f; pp = 1.0f; pd = 0.0f; }
            else           { pn = pp = pd = (1.0f / 2048.0f); }  // all -1e9
            pvals[r] = make_float4(pn, pp, pd, 0.0f);
        }
    }
}

// ---------- K2: per-batch prefix sums of l_q (double accumulation) ----------
__global__ __launch_bounds__(256) void scan_kernel(
    const float4* __restrict__ pvals, const float* __restrict__ prior,
    float* __restrict__ P) {
    int b = blockIdx.x, t = threadIdx.x;
    int base_s = t * 8;
    double loc[8];
    double run = 0.0;
#pragma unroll
    for (int i = 0; i < 8; i++) {
        loc[i] = run;
        int s = base_s + i;
        float lv = 0.0f;
        if (s < SS - 1) {
            int r = b * SS + s;
            float4 pv = pvals[r];
            float4 pv1 = pvals[r + 1];
            float ns = sqrtf(pv.x * pv1.y + 1e-9f);
            float pr = prior[(size_t)b * SS * SS + (size_t)s * SS + s + 1];
            float neib = pr + (1.0f - pr) * ns;
            lv = logf(neib + 1e-9f);
        }
        run += (double)lv;
    }
    int lane = t & 63, wave = t >> 6;
    double v = run;
#pragma unroll
    for (int off = 1; off < 64; off <<= 1) {
        double uu = __shfl_up(v, off, 64);
        if (lane >= off) v += uu;
    }
    __shared__ double wsum[4];
    if (lane == 63) wsum[wave] = v;
    __syncthreads();
    double woff = 0.0;
    for (int w = 0; w < wave; w++) woff += wsum[w];
    double texcl = woff + (v - run);  // exclusive prefix of thread totals
#pragma unroll
    for (int i = 0; i < 8; i++)
        P[b * SS + base_s + i] = (float)(texcl + loc[i]);
}

// ---------- K3: fill output G[b,i,j] ----------
__global__ __launch_bounds__(256) void fill_kernel(
    const float* __restrict__ P, const float4* __restrict__ pvals,
    const float* __restrict__ prior, float* __restrict__ out) {
    int blk = blockIdx.x;  // r = b*S + i
    int i = blk & (SS - 1), b = blk >> 11;
    int t = threadIdx.x;
    __shared__ float shPi, shDv;
    if (t == 0) {
        shPi = P[blk];
        float pd = pvals[blk].z;
        float prd = prior[(size_t)b * SS * SS + (size_t)i * SS + i];
        shDv = prd + (1.0f - prd) * sqrtf(pd * pd + 1e-9f);
    }
    __syncthreads();
    float Pi = shPi, dv = shDv;
    const float* Pb = P + b * SS;
    size_t outbase = (size_t)blk * SS;
    float4 pj0 = *(const float4*)(Pb + t * 8);
    float4 pj1 = *(const float4*)(Pb + t * 8 + 4);
    float pj[8] = {pj0.x, pj0.y, pj0.z, pj0.w, pj1.x, pj1.y, pj1.z, pj1.w};
    float res[8];
#pragma unroll
    for (int k = 0; k < 8; k++) {
        int j = t * 8 + k;
        float d = (j > i) ? (pj[k] - Pi) : (Pi - pj[k]);
        float val = __expf(d) + 1e-9f;
        res[k] = (j == i) ? dv : val;
    }
    *(float4*)(out + outbase + t * 8) = make_float4(res[0], res[1], res[2], res[3]);
    *(float4*)(out + outbase + t * 8 + 4) = make_float4(res[4], res[5], res[6], res[7]);
}

extern "C" void kernel_launch(void* const* d_in, const int* in_sizes, int n_in,
                              void* d_out, int out_size, void* d_ws, size_t ws_size,
                              hipStream_t stream) {
    const float* context = (const float*)d_in[0];
    const float* prior   = (const float*)d_in[1];
    const float* Wq      = (const float*)d_in[2];
    const float* bq      = (const float*)d_in[3];
    const float* Wk      = (const float*)d_in[4];
    // bk (d_in[5]) cancels in the score difference
    const float* ln_a    = (const float*)d_in[6];
    const float* ln_b    = (const float*)d_in[7];
    const int*   eos     = (const int*)d_in[8];
    float* out = (float*)d_out;

    float* ws = (float*)d_ws;
    float* A     = ws;                       // 65536 floats
    float* u     = ws + 65536;               // 256
    float4* pv   = (float4*)(ws + 65792);    // 8192 float4 = 32768 floats
    float* P     = ws + 98560;               // 8192

    prep_kernel<<<DD + 1, 256, 0, stream>>>(Wq, Wk, bq, A, u);
    gemm_score_kernel<<<NR / 32, 256, 0, stream>>>(
        (const float4*)context, (const float4*)ln_a, (const float4*)ln_b,
        A, u, eos, pv);
    scan_kernel<<<NB, 256, 0, stream>>>(pv, prior, P);
    fill_kernel<<<NR, 256, 0, stream>>>(P, pv, prior, out);
}